// Round 1
// baseline (301.657 us; speedup 1.0000x reference)
//
#include <hip/hip_runtime.h>

#define NUM_CODES 512
#define DIM 64
#define NPIX (32 * 64 * 64)   // 131072 pixels

// ---------------------------------------------------------------------------
// Kernel A: per-code squared L2 norm of embeddings, numpy-pairwise order
// (8 accumulators over d%8, then tree combine) to track np.sum semantics.
// ---------------------------------------------------------------------------
__global__ void l2e_kernel(const float* __restrict__ emb,
                           float* __restrict__ l2e) {
    int k = blockIdx.x * blockDim.x + threadIdx.x;
    if (k >= NUM_CODES) return;
    const float* e = emb + k * DIM;
    float r[8];
#pragma unroll
    for (int j = 0; j < 8; ++j) {
        float v = e[j];
        r[j] = v * v;
    }
#pragma unroll
    for (int i = 8; i < DIM; i += 8) {
#pragma unroll
        for (int j = 0; j < 8; ++j) {
            float v = e[i + j];
            r[j] += v * v;
        }
    }
    float s = ((r[0] + r[1]) + (r[2] + r[3])) + ((r[4] + r[5]) + (r[6] + r[7]));
    l2e[k] = s;
}

// ---------------------------------------------------------------------------
// Kernel B: one thread per pixel. x[64] lives in VGPRs; embeddings are read
// with wave-uniform indices (k,d are loop counters) so the compiler can use
// scalar loads (SMEM path, no VALU/LDS cost). Distances follow the reference
// formula (l2x + l2e[k]) - 2*dot in fp32; strict '<' keeps the lowest index
// on ties, matching np.argmin.
// ---------------------------------------------------------------------------
__global__ __launch_bounds__(256) void vq_kernel(
    const float* __restrict__ x_in, const float* __restrict__ emb,
    const float* __restrict__ l2e, float* __restrict__ codes_out,
    float* __restrict__ vecs_out) {
    int pix = blockIdx.x * 256 + threadIdx.x;

    const float* xp = x_in + (size_t)pix * DIM;
    float x[DIM];
#pragma unroll
    for (int j = 0; j < DIM / 4; ++j) {
        float4 v = ((const float4*)xp)[j];
        x[4 * j + 0] = v.x;
        x[4 * j + 1] = v.y;
        x[4 * j + 2] = v.z;
        x[4 * j + 3] = v.w;
    }

    // ||x||^2, numpy-pairwise 8-accumulator order
    float r[8];
#pragma unroll
    for (int j = 0; j < 8; ++j) r[j] = x[j] * x[j];
#pragma unroll
    for (int i = 8; i < DIM; i += 8) {
#pragma unroll
        for (int j = 0; j < 8; ++j) r[j] += x[i + j] * x[i + j];
    }
    float l2x =
        ((r[0] + r[1]) + (r[2] + r[3])) + ((r[4] + r[5]) + (r[6] + r[7]));

    float best = 3.4e38f;
    int bi = 0;
    for (int k = 0; k < NUM_CODES; ++k) {
        const float* e = emb + k * DIM;  // wave-uniform address
        float acc = 0.0f;
#pragma unroll
        for (int d = 0; d < DIM; ++d) acc = __builtin_fmaf(x[d], e[d], acc);
        float dist = (l2x + l2e[k]) - 2.0f * acc;
        if (dist < best) {
            best = dist;
            bi = k;
        }
    }

    codes_out[pix] = (float)bi;  // harness reads non-bf16 outputs as float32

    float* vo = vecs_out + (size_t)pix * DIM;
    const float* eb = emb + bi * DIM;
#pragma unroll
    for (int j = 0; j < DIM / 4; ++j) {
        ((float4*)vo)[j] = ((const float4*)eb)[j];
    }
}

extern "C" void kernel_launch(void* const* d_in, const int* in_sizes, int n_in,
                              void* d_out, int out_size, void* d_ws,
                              size_t ws_size, hipStream_t stream) {
    const float* x_in = (const float*)d_in[0];   // [32,64,64,64] fp32
    const float* emb = (const float*)d_in[1];    // [512,64] fp32

    float* l2e = (float*)d_ws;                   // 512 floats scratch
    float* codes_out = (float*)d_out;            // first NPIX floats
    float* vecs_out = (float*)d_out + NPIX;      // then NPIX*DIM floats

    hipLaunchKernelGGL(l2e_kernel, dim3(2), dim3(256), 0, stream, emb, l2e);
    hipLaunchKernelGGL(vq_kernel, dim3(NPIX / 256), dim3(256), 0, stream, x_in,
                       emb, l2e, codes_out, vecs_out);
}

// Round 2
// 189.705 us; speedup vs baseline: 1.5901x; 1.5901x over previous
//
#include <hip/hip_runtime.h>

#define NUM_CODES 512
#define DIM 64
#define NPIX (32 * 64 * 64)   // 131072 pixels
#define PIX_PER_BLK 128
#define BLK 256               // 4 waves: teams {w0,w1}=codes 0-255, {w2,w3}=codes 256-511

// One fused kernel:
//  phase 0: all threads compute ||e_k||^2 into LDS (identical op order every
//           block -> identical values, numpy-pairwise 8-acc emulation)
//  phase 1: each thread owns 1 pixel and scans 256 codes (its team's half);
//           x[64] in VGPRs, embedding rows via wave-uniform scalar loads,
//           4 independent FMA accumulators.
//  phase 2: LDS combine of the two team candidates (dlow <= dhigh keeps the
//           lower code index on exact ties = np.argmin first-min semantics),
//           then fully-coalesced cooperative gather of code_vecs.
__global__ __launch_bounds__(BLK, 4) void vq_kernel(
    const float* __restrict__ x_in, const float* __restrict__ emb,
    float* __restrict__ codes_out, float* __restrict__ vecs_out) {
    __shared__ float s_l2e[NUM_CODES];
    __shared__ float s_best[PIX_PER_BLK];
    __shared__ int s_bi[PIX_PER_BLK];
    __shared__ int s_code[PIX_PER_BLK];

    const int tid = threadIdx.x;

    // ---- phase 0: ||e||^2 for all 512 codes (2 per thread) ----
#pragma unroll
    for (int c = 0; c < 2; ++c) {
        const int k = tid + c * BLK;
        const float* e = emb + k * DIM;
        float r[8];
#pragma unroll
        for (int j = 0; j < 8; ++j) {
            float v = e[j];
            r[j] = v * v;
        }
#pragma unroll
        for (int i = 8; i < DIM; i += 8) {
#pragma unroll
            for (int j = 0; j < 8; ++j) {
                float v = e[i + j];
                r[j] += v * v;
            }
        }
        s_l2e[k] =
            ((r[0] + r[1]) + (r[2] + r[3])) + ((r[4] + r[5]) + (r[6] + r[7]));
    }
    __syncthreads();

    // ---- phase 1: per-pixel scan of this team's 256 codes ----
    const int pi = tid & (PIX_PER_BLK - 1);                       // pixel in block
    const int team = __builtin_amdgcn_readfirstlane(tid >> 7);    // wave-uniform
    const int kbase = team << 8;
    const int pix = blockIdx.x * PIX_PER_BLK + pi;

    float x[DIM];
    const float4* xp4 = (const float4*)(x_in + (size_t)pix * DIM);
#pragma unroll
    for (int j = 0; j < DIM / 4; ++j) {
        float4 v = xp4[j];
        x[4 * j + 0] = v.x;
        x[4 * j + 1] = v.y;
        x[4 * j + 2] = v.z;
        x[4 * j + 3] = v.w;
    }

    // ||x||^2, numpy-pairwise 8-acc order (matches reference path)
    float r[8];
#pragma unroll
    for (int j = 0; j < 8; ++j) r[j] = x[j] * x[j];
#pragma unroll
    for (int i = 8; i < DIM; i += 8) {
#pragma unroll
        for (int j = 0; j < 8; ++j) r[j] += x[i + j] * x[i + j];
    }
    const float l2x =
        ((r[0] + r[1]) + (r[2] + r[3])) + ((r[4] + r[5]) + (r[6] + r[7]));

    float best = 3.4e38f;
    int bi = kbase;
    for (int k = 0; k < NUM_CODES / 2; ++k) {
        const float* e = emb + (size_t)(kbase + k) * DIM;  // wave-uniform -> s_load
        float a0 = 0.f, a1 = 0.f, a2 = 0.f, a3 = 0.f;
#pragma unroll
        for (int d = 0; d < DIM; d += 4) {
            a0 = __builtin_fmaf(x[d + 0], e[d + 0], a0);
            a1 = __builtin_fmaf(x[d + 1], e[d + 1], a1);
            a2 = __builtin_fmaf(x[d + 2], e[d + 2], a2);
            a3 = __builtin_fmaf(x[d + 3], e[d + 3], a3);
        }
        const float acc = (a0 + a1) + (a2 + a3);
        const float dist = (l2x + s_l2e[kbase + k]) - 2.0f * acc;
        if (dist < best) {
            best = dist;
            bi = kbase + k;
        }
    }

    // ---- phase 2: combine teams ----
    if (team == 1) {
        s_best[pi] = best;
        s_bi[pi] = bi;
    }
    __syncthreads();
    if (team == 0) {
        const float dh = s_best[pi];
        const int bh = s_bi[pi];
        const int sel = (best <= dh) ? bi : bh;  // tie -> lower index (team 0)
        s_code[pi] = sel;
        codes_out[pix] = (float)sel;
    }
    __syncthreads();

    // cooperative fully-coalesced gather: 128 pixels * 16 float4 = 2048 float4
    const float4* emb4 = (const float4*)emb;
    float4* vout4 = (float4*)(vecs_out + (size_t)blockIdx.x * PIX_PER_BLK * DIM);
#pragma unroll
    for (int j = 0; j < (PIX_PER_BLK * DIM / 4) / BLK; ++j) {
        const int f = tid + j * BLK;   // [0, 2048)
        const int p = f >> 4;          // pixel within block
        const int d4 = f & 15;
        vout4[f] = emb4[(size_t)s_code[p] * (DIM / 4) + d4];
    }
}

extern "C" void kernel_launch(void* const* d_in, const int* in_sizes, int n_in,
                              void* d_out, int out_size, void* d_ws,
                              size_t ws_size, hipStream_t stream) {
    const float* x_in = (const float*)d_in[0];  // [32,64,64,64] fp32
    const float* emb = (const float*)d_in[1];   // [512,64] fp32

    float* codes_out = (float*)d_out;           // NPIX floats (int codes as f32)
    float* vecs_out = (float*)d_out + NPIX;     // NPIX*DIM floats

    hipLaunchKernelGGL(vq_kernel, dim3(NPIX / PIX_PER_BLK), dim3(BLK), 0,
                       stream, x_in, emb, codes_out, vecs_out);
}